// Round 6
// baseline (103.414 us; speedup 1.0000x reference)
//
#include <hip/hip_runtime.h>

// VQ codebook assign: argmin_k ||x-w_k||^2 = argmax_k (x.w_k - 0.5||w_k||^2)
// Round 6: single-pass FP16 MFMA (u=2^-11 -> score-diff noise ~3.2e-3 sigma;
// EPS_GAP=1/32 is a ~10-sigma guard), bias injected via MFMA C-in (no movs),
// med3-based top-2 (4 VALU/score), near-ties -> worklist -> coalesced fp64
// fixup kernel (512 blocks). Main loop: no LDS, no barriers, 2-stage A-frag
// prefetch from a 128KB L2-resident pre-swizzled fp16 codebook.
//
// ws: bias[1024]f32 @0 | rec fp16 @4096 (128KB) | cnt @135168 | list @135184

#define BB 32
#define DD 64
#define TT 4096
#define KK 1024
#define EPS_GAP 0.03125f

#define REC_OFF  4096
#define CNT_OFF  135168
#define LIST_OFF 135184

typedef __attribute__((ext_vector_type(8))) _Float16 half8;
typedef __attribute__((ext_vector_type(4))) float f32x4;

// ---- prep: weight -> swizzled fp16 A-frag records + bias; reset cnt ----
// record r = kc*4 + ks*2 + c (0..127): lane l holds code kc*32+c*16+(l&15),
// d = ks*32+(l>>4)*8+e, 8 halves = 16B. 128 recs * 1KB = 128KB.
__global__ __launch_bounds__(256) void vq_prep(
    const float* __restrict__ w, float* __restrict__ bias,
    _Float16* __restrict__ rec, int* __restrict__ cnt)
{
    const int g    = blockIdx.x * 256 + threadIdx.x;   // 0..8191
    if (g == 0) *cnt = 0;
    const int lane = g & 63;
    const int r    = g >> 6;                           // record 0..127
    const int kc   = r >> 2, ks = (r >> 1) & 1, c = r & 1;
    const int code  = kc * 32 + c * 16 + (lane & 15);
    const int dbase = ks * 32 + (lane >> 4) * 8;

    const float* src = w + (size_t)code * DD + dbase;
    float4 f0 = *(const float4*)src;
    float4 f1 = *(const float4*)(src + 4);
    half8 hv;
    hv[0] = (_Float16)f0.x; hv[1] = (_Float16)f0.y;
    hv[2] = (_Float16)f0.z; hv[3] = (_Float16)f0.w;
    hv[4] = (_Float16)f1.x; hv[5] = (_Float16)f1.y;
    hv[6] = (_Float16)f1.z; hv[7] = (_Float16)f1.w;
    *(half8*)(rec + (size_t)r * 512 + lane * 8) = hv;

    if (g < KK) {
        const float4* wp = (const float4*)(w + (size_t)g * DD);
        float s = 0.f;
        #pragma unroll
        for (int j = 0; j < 16; ++j) {
            float4 v = wp[j];
            s += v.x * v.x + v.y * v.y + v.z * v.z + v.w * v.w;
        }
        bias[g] = -0.5f * s;
    }
}

// ---- main: 4 waves x 64 points per block, 512 blocks ----
__global__ __launch_bounds__(256, 2) void vq_main(
    const float* __restrict__ x,
    const float* __restrict__ weight,
    const float* __restrict__ bias,
    const _Float16* __restrict__ rec,
    int* __restrict__ cnt, int* __restrict__ list, int cap,
    float* __restrict__ out)
{
    const int tid  = threadIdx.x;
    const int lane = tid & 63;
    const int wv   = tid >> 6;
    const int b    = blockIdx.x >> 4;                  // 16 tiles of 256 pts per batch
    const int t0   = (blockIdx.x & 15) << 8;
    const int col  = lane & 15, kg = lane >> 4;

    // x -> fp16 B-frags straight from global
    half8 Bf[4][2];                                    // [pt-tile][kstep]
    {
        const float* xb = x + (size_t)b * DD * TT + t0 + wv * 64 + col;
        #pragma unroll
        for (int p = 0; p < 4; ++p)
            #pragma unroll
            for (int ks = 0; ks < 2; ++ks) {
                half8 hv;
                #pragma unroll
                for (int e = 0; e < 8; ++e)
                    hv[e] = (_Float16)xb[(size_t)(ks * 32 + kg * 8 + e) * TT + p * 16];
                Bf[p][ks] = hv;
            }
    }

    float s1[4] = {-1e30f, -1e30f, -1e30f, -1e30f};
    float s2[4] = {-1e30f, -1e30f, -1e30f, -1e30f};
    int   k1[4] = {0, 0, 0, 0};

    auto loadA = [&](int kc, half8 (*A)[2]) {
        #pragma unroll
        for (int ks = 0; ks < 2; ++ks)
            #pragma unroll
            for (int c = 0; c < 2; ++c)
                A[ks][c] = *(const half8*)(rec + (size_t)(kc * 4 + ks * 2 + c) * 512 + lane * 8);
    };
    auto compute = [&](int kc, half8 (*A)[2]) {
        f32x4 acc[2][4];                               // [c-tile][pt-tile]
        #pragma unroll
        for (int c = 0; c < 2; ++c) {
            const f32x4 bv = *(const f32x4*)(bias + kc * 32 + c * 16 + kg * 4);
            #pragma unroll
            for (int p = 0; p < 4; ++p) {
                // bias enters as MFMA C-in: no acc-init movs
                acc[c][p] = __builtin_amdgcn_mfma_f32_16x16x32_f16(A[0][c], Bf[p][0], bv, 0, 0, 0);
                acc[c][p] = __builtin_amdgcn_mfma_f32_16x16x32_f16(A[1][c], Bf[p][1], acc[c][p], 0, 0, 0);
            }
        }
        #pragma unroll
        for (int p = 0; p < 4; ++p)
            #pragma unroll
            for (int c = 0; c < 2; ++c)
                #pragma unroll
                for (int r = 0; r < 4; ++r) {
                    const float s = acc[c][p][r];
                    const int code = kc * 32 + c * 16 + kg * 4 + r;
                    // s2 = med3(s, s1, s2); s1/k1 via cmp+cndmask (4 VALU/score)
                    const float ns2 = fmaxf(fminf(s, s1[p]), s2[p]);
                    if (s > s1[p]) { k1[p] = code; s1[p] = s; }
                    s2[p] = ns2;
                }
    };

    // K loop: 32 chunks, 2-stage prefetch pipeline
    half8 A0[2][2], A1[2][2];
    loadA(0, A0);
    for (int kc = 0; kc < 32; kc += 2) {
        loadA(kc + 1, A1);
        compute(kc, A0);
        if (kc + 2 < 32) loadA(kc + 2, A0);
        compute(kc + 1, A1);
    }

    // cross-lane merge: lanes l, l^16, l^32, l^48 share a point
    #pragma unroll
    for (int p = 0; p < 4; ++p) {
        #pragma unroll
        for (int off = 16; off < 64; off <<= 1) {
            float o1 = __shfl_xor(s1[p], off, 64);
            float o2 = __shfl_xor(s2[p], off, 64);
            int   ok = __shfl_xor(k1[p], off, 64);
            bool takeo = (o1 > s1[p]) || (o1 == s1[p] && ok < k1[p]);
            float ns2 = fmaxf(fminf(s1[p], o1), fmaxf(s2[p], o2));
            if (takeo) { s1[p] = o1; k1[p] = ok; }
            s2[p] = ns2;
        }

        // near-tie: push to worklist (fixup kernel resolves exactly)
        bool flag = (lane < 16) && ((s1[p] - s2[p]) <= EPS_GAP);
        int slot = -1;
        if (flag) slot = atomicAdd(cnt, 1);
        if (flag && slot < cap)
            list[slot] = b * TT + t0 + wv * 64 + p * 16 + lane;

        // overflow fallback: inline exact fp64 re-scan (practically never)
        unsigned long long m = __ballot(flag && slot >= cap);
        while (m) {
            const int ptt = __ffsll(m) - 1; m &= m - 1;
            const int t = t0 + wv * 64 + p * 16 + ptt;
            const float* xp = x + (size_t)b * DD * TT + t;
            double bd = 1e300; int bk = 0;
            for (int j = 0; j < 16; ++j) {
                const int k = lane + 64 * j;
                const float* wk = weight + (size_t)k * DD;
                double a0 = 0.0, a1 = 0.0;
                #pragma unroll
                for (int d = 0; d < DD; d += 2) {
                    double e0 = (double)xp[(size_t)d * TT]       - (double)wk[d];
                    double e1 = (double)xp[(size_t)(d + 1) * TT] - (double)wk[d + 1];
                    a0 = fma(e0, e0, a0);
                    a1 = fma(e1, e1, a1);
                }
                const double dist = a0 + a1;
                if (dist < bd || (dist == bd && k < bk)) { bd = dist; bk = k; }
            }
            #pragma unroll
            for (int off = 1; off < 64; off <<= 1) {
                double od = __shfl_xor(bd, off, 64);
                int    okk = __shfl_xor(bk, off, 64);
                if (od < bd || (od == bd && okk < bk)) { bd = od; bk = okk; }
            }
            if ((lane & 15) == ptt) k1[p] = bk;
        }
    }

    // epilogue: distribute indices via shfl; lane owns point lane
    const int q0 = __shfl(k1[0], lane & 15, 64);
    const int q1 = __shfl(k1[1], lane & 15, 64);
    const int q2 = __shfl(k1[2], lane & 15, 64);
    const int q3 = __shfl(k1[3], lane & 15, 64);
    const int hp = lane >> 4;
    const int kq = (hp == 0) ? q0 : (hp == 1) ? q1 : (hp == 2) ? q2 : q3;

    const int t = t0 + wv * 64 + lane;
    out[(size_t)BB * DD * TT + (size_t)b * TT + t] = (float)kq;

    // quantized: lane writes its point's full column (64 d), coalesced across lanes
    {
        const float4* wr = (const float4*)(weight + (size_t)kq * DD);
        float* op = out + (size_t)b * DD * TT + t;
        #pragma unroll
        for (int jq = 0; jq < 16; ++jq) {
            float4 v = wr[jq];
            op[(size_t)(jq * 4 + 0) * TT] = v.x;
            op[(size_t)(jq * 4 + 1) * TT] = v.y;
            op[(size_t)(jq * 4 + 2) * TT] = v.z;
            op[(size_t)(jq * 4 + 3) * TT] = v.w;
        }
    }
}

// ---- fixup: flagged points, coalesced exact fp64 full scan ----
__global__ __launch_bounds__(256) void vq_fixup(
    const float* __restrict__ x, const float* __restrict__ w,
    const int* __restrict__ cnt, const int* __restrict__ list, int cap,
    float* __restrict__ out)
{
    __shared__ double sd[4];
    __shared__ int    sk[4];
    int n = *cnt; if (n > cap) n = cap;

    for (int i = blockIdx.x; i < n; i += gridDim.x) {
        const int g = list[i];
        const int b = g >> 12;             // TT = 4096
        const int t = g & (TT - 1);
        const float* xp = x + (size_t)b * DD * TT + t;

        const int quarter = threadIdx.x & 3;       // 16 d's each
        const int cbase   = threadIdx.x >> 2;      // 0..63

        double xq[16];
        #pragma unroll
        for (int j = 0; j < 16; ++j)
            xq[j] = (double)xp[(size_t)(quarter * 16 + j) * TT];

        double bd = 1e300; int bk = 0;
        for (int it = 0; it < 16; ++it) {
            const int code = cbase + (it << 6);
            const float4* wr = (const float4*)(w + (size_t)code * DD + quarter * 16);
            double a = 0.0;
            #pragma unroll
            for (int q4 = 0; q4 < 4; ++q4) {
                float4 v = wr[q4];
                double e0 = xq[q4 * 4 + 0] - (double)v.x;
                double e1 = xq[q4 * 4 + 1] - (double)v.y;
                double e2 = xq[q4 * 4 + 2] - (double)v.z;
                double e3 = xq[q4 * 4 + 3] - (double)v.w;
                a = fma(e0, e0, a); a = fma(e1, e1, a);
                a = fma(e2, e2, a); a = fma(e3, e3, a);
            }
            a += __shfl_xor(a, 1, 64);
            a += __shfl_xor(a, 2, 64);
            if (a < bd || (a == bd && code < bk)) { bd = a; bk = code; }
        }
        #pragma unroll
        for (int off = 4; off < 64; off <<= 1) {
            double od = __shfl_xor(bd, off, 64);
            int    ok = __shfl_xor(bk, off, 64);
            if (od < bd || (od == bd && ok < bk)) { bd = od; bk = ok; }
        }
        if ((threadIdx.x & 63) == 0) { sd[threadIdx.x >> 6] = bd; sk[threadIdx.x >> 6] = bk; }
        __syncthreads();
        double fb = sd[0]; int fk = sk[0];
        #pragma unroll
        for (int wvi = 1; wvi < 4; ++wvi)
            if (sd[wvi] < fb || (sd[wvi] == fb && sk[wvi] < fk)) { fb = sd[wvi]; fk = sk[wvi]; }

        if (threadIdx.x == 0)
            out[(size_t)BB * DD * TT + g] = (float)fk;
        if (threadIdx.x < 64)
            out[(size_t)b * DD * TT + (size_t)threadIdx.x * TT + t] = w[(size_t)fk * DD + threadIdx.x];
        __syncthreads();   // sd/sk reuse across iterations
    }
}

extern "C" void kernel_launch(void* const* d_in, const int* in_sizes, int n_in,
                              void* d_out, int out_size, void* d_ws, size_t ws_size,
                              hipStream_t stream) {
    const float* x      = (const float*)d_in[0];
    const float* weight = (const float*)d_in[1];
    float* out = (float*)d_out;

    float* bias     = (float*)d_ws;
    _Float16* rec   = (_Float16*)((char*)d_ws + REC_OFF);
    int* cnt        = (int*)((char*)d_ws + CNT_OFF);
    int* list       = (int*)((char*)d_ws + LIST_OFF);
    long long avail = (long long)ws_size - LIST_OFF;
    int cap = avail > 0 ? (int)(avail / 4) : 0;
    if (cap > BB * TT) cap = BB * TT;

    vq_prep<<<32, 256, 0, stream>>>(weight, bias, rec, cnt);
    vq_main<<<(BB * TT) / 256, 256, 0, stream>>>(x, weight, bias, rec, cnt, list, cap, out);
    vq_fixup<<<512, 256, 0, stream>>>(x, weight, cnt, list, cap, out);
}

// Round 7
// 85.682 us; speedup vs baseline: 1.2069x; 1.2069x over previous
//
#include <hip/hip_runtime.h>

// VQ codebook assign: argmin_k ||x-w_k||^2 = argmax_k (x.w_k - 0.5||w_k||^2)
// Round 7: occupancy fix. 32 points/wave (2 pt-tiles), grid 1024,
// __launch_bounds__(256,4) -> 4 blocks/CU = 4 waves/SIMD (was 2). Single-pass
// FP16 MFMA (noise sigma ~3.2e-3), EPS_GAP=1/64 (~5 sigma), bias via MFMA
// C-in, near-ties -> atomic worklist -> coalesced fp64 fixup (1024 blocks).
//
// ws: bias[1024]f32 @0 | rec fp16 @4096 (128KB) | cnt @135168 | list @135184

#define BB 32
#define DD 64
#define TT 4096
#define KK 1024
#define EPS_GAP 0.015625f

#define REC_OFF  4096
#define CNT_OFF  135168
#define LIST_OFF 135184

typedef __attribute__((ext_vector_type(8))) _Float16 half8;
typedef __attribute__((ext_vector_type(4))) float f32x4;

// ---- prep: weight -> swizzled fp16 A-frag records + bias; reset cnt ----
// record r = kc*4 + ks*2 + c (0..127): lane l holds code kc*32+c*16+(l&15),
// d = ks*32+(l>>4)*8+e, 8 halves = 16B. 128 recs * 1KB = 128KB.
__global__ __launch_bounds__(256) void vq_prep(
    const float* __restrict__ w, float* __restrict__ bias,
    _Float16* __restrict__ rec, int* __restrict__ cnt)
{
    const int g    = blockIdx.x * 256 + threadIdx.x;   // 0..8191
    if (g == 0) *cnt = 0;
    const int lane = g & 63;
    const int r    = g >> 6;                           // record 0..127
    const int kc   = r >> 2, ks = (r >> 1) & 1, c = r & 1;
    const int code  = kc * 32 + c * 16 + (lane & 15);
    const int dbase = ks * 32 + (lane >> 4) * 8;

    const float* src = w + (size_t)code * DD + dbase;
    float4 f0 = *(const float4*)src;
    float4 f1 = *(const float4*)(src + 4);
    half8 hv;
    hv[0] = (_Float16)f0.x; hv[1] = (_Float16)f0.y;
    hv[2] = (_Float16)f0.z; hv[3] = (_Float16)f0.w;
    hv[4] = (_Float16)f1.x; hv[5] = (_Float16)f1.y;
    hv[6] = (_Float16)f1.z; hv[7] = (_Float16)f1.w;
    *(half8*)(rec + (size_t)r * 512 + lane * 8) = hv;

    if (g < KK) {
        const float4* wp = (const float4*)(w + (size_t)g * DD);
        float s = 0.f;
        #pragma unroll
        for (int j = 0; j < 16; ++j) {
            float4 v = wp[j];
            s += v.x * v.x + v.y * v.y + v.z * v.z + v.w * v.w;
        }
        bias[g] = -0.5f * s;
    }
}

// ---- main: 4 waves x 32 points per block, 1024 blocks (4 blocks/CU) ----
__global__ __launch_bounds__(256, 4) void vq_main(
    const float* __restrict__ x,
    const float* __restrict__ weight,
    const float* __restrict__ bias,
    const _Float16* __restrict__ rec,
    int* __restrict__ cnt, int* __restrict__ list, int cap,
    float* __restrict__ out)
{
    const int tid  = threadIdx.x;
    const int lane = tid & 63;
    const int wv   = tid >> 6;
    const int b    = blockIdx.x >> 5;                  // 32 tiles of 128 pts per batch
    const int t0   = (blockIdx.x & 31) << 7;
    const int col  = lane & 15, kg = lane >> 4;

    // x -> fp16 B-frags straight from global
    half8 Bf[2][2];                                    // [pt-tile][kstep]
    {
        const float* xb = x + (size_t)b * DD * TT + t0 + wv * 32 + col;
        #pragma unroll
        for (int p = 0; p < 2; ++p)
            #pragma unroll
            for (int ks = 0; ks < 2; ++ks) {
                half8 hv;
                #pragma unroll
                for (int e = 0; e < 8; ++e)
                    hv[e] = (_Float16)xb[(size_t)(ks * 32 + kg * 8 + e) * TT + p * 16];
                Bf[p][ks] = hv;
            }
    }

    float s1[2] = {-1e30f, -1e30f};
    float s2[2] = {-1e30f, -1e30f};
    int   k1[2] = {0, 0};

    auto loadA = [&](int kc, half8 (*A)[2]) {
        #pragma unroll
        for (int ks = 0; ks < 2; ++ks)
            #pragma unroll
            for (int c = 0; c < 2; ++c)
                A[ks][c] = *(const half8*)(rec + (size_t)(kc * 4 + ks * 2 + c) * 512 + lane * 8);
    };
    auto compute = [&](int kc, half8 (*A)[2]) {
        f32x4 acc[2][2];                               // [c-tile][pt-tile]
        #pragma unroll
        for (int c = 0; c < 2; ++c) {
            const f32x4 bv = *(const f32x4*)(bias + kc * 32 + c * 16 + kg * 4);
            #pragma unroll
            for (int p = 0; p < 2; ++p) {
                // bias enters as MFMA C-in: no acc-init movs
                acc[c][p] = __builtin_amdgcn_mfma_f32_16x16x32_f16(A[0][c], Bf[p][0], bv, 0, 0, 0);
                acc[c][p] = __builtin_amdgcn_mfma_f32_16x16x32_f16(A[1][c], Bf[p][1], acc[c][p], 0, 0, 0);
            }
        }
        #pragma unroll
        for (int p = 0; p < 2; ++p)
            #pragma unroll
            for (int c = 0; c < 2; ++c)
                #pragma unroll
                for (int r = 0; r < 4; ++r) {
                    const float s = acc[c][p][r];
                    const int code = kc * 32 + c * 16 + kg * 4 + r;
                    const float ns2 = fmaxf(fminf(s, s1[p]), s2[p]);
                    if (s > s1[p]) { k1[p] = code; s1[p] = s; }
                    s2[p] = ns2;
                }
    };

    // K loop: 32 chunks, 2-stage prefetch pipeline
    half8 A0[2][2], A1[2][2];
    loadA(0, A0);
    for (int kc = 0; kc < 32; kc += 2) {
        loadA(kc + 1, A1);
        compute(kc, A0);
        if (kc + 2 < 32) loadA(kc + 2, A0);
        compute(kc + 1, A1);
    }

    // cross-lane merge: lanes l, l^16, l^32, l^48 share a point
    #pragma unroll
    for (int p = 0; p < 2; ++p) {
        #pragma unroll
        for (int off = 16; off < 64; off <<= 1) {
            float o1 = __shfl_xor(s1[p], off, 64);
            float o2 = __shfl_xor(s2[p], off, 64);
            int   ok = __shfl_xor(k1[p], off, 64);
            bool takeo = (o1 > s1[p]) || (o1 == s1[p] && ok < k1[p]);
            float ns2 = fmaxf(fminf(s1[p], o1), fmaxf(s2[p], o2));
            if (takeo) { s1[p] = o1; k1[p] = ok; }
            s2[p] = ns2;
        }

        // near-tie: push to worklist (fixup kernel resolves exactly)
        bool flag = (lane < 16) && ((s1[p] - s2[p]) <= EPS_GAP);
        int slot = -1;
        if (flag) slot = atomicAdd(cnt, 1);
        if (flag && slot < cap)
            list[slot] = b * TT + t0 + wv * 32 + p * 16 + lane;

        // overflow fallback: inline exact fp64 re-scan (practically never)
        unsigned long long m = __ballot(flag && slot >= cap);
        while (m) {
            const int ptt = __ffsll(m) - 1; m &= m - 1;
            const int t = t0 + wv * 32 + p * 16 + ptt;
            const float* xp = x + (size_t)b * DD * TT + t;
            double bd = 1e300; int bk = 0;
            for (int j = 0; j < 16; ++j) {
                const int k = lane + 64 * j;
                const float* wk = weight + (size_t)k * DD;
                double a0 = 0.0, a1 = 0.0;
                #pragma unroll
                for (int d = 0; d < DD; d += 2) {
                    double e0 = (double)xp[(size_t)d * TT]       - (double)wk[d];
                    double e1 = (double)xp[(size_t)(d + 1) * TT] - (double)wk[d + 1];
                    a0 = fma(e0, e0, a0);
                    a1 = fma(e1, e1, a1);
                }
                const double dist = a0 + a1;
                if (dist < bd || (dist == bd && k < bk)) { bd = dist; bk = k; }
            }
            #pragma unroll
            for (int off = 1; off < 64; off <<= 1) {
                double od = __shfl_xor(bd, off, 64);
                int    okk = __shfl_xor(bk, off, 64);
                if (od < bd || (od == bd && okk < bk)) { bd = od; bk = okk; }
            }
            if ((lane & 15) == ptt) k1[p] = bk;
        }
    }

    // epilogue: lane owns point ptl = lane&31; two lanes per point write 32 d each
    const int ptl = lane & 31;
    const int q0 = __shfl(k1[0], lane & 15, 64);
    const int q1 = __shfl(k1[1], lane & 15, 64);
    const int kq = (ptl & 16) ? q1 : q0;

    if (lane < 32)
        out[(size_t)BB * DD * TT + (size_t)b * TT + t0 + wv * 32 + lane] = (float)kq;

    {
        const int half = lane >> 5;
        const float4* wr = (const float4*)(weight + (size_t)kq * DD + half * 32);
        float* op = out + ((size_t)b * DD + half * 32) * TT + t0 + wv * 32 + ptl;
        #pragma unroll
        for (int jq = 0; jq < 8; ++jq) {
            float4 v = wr[jq];
            op[(size_t)(jq * 4 + 0) * TT] = v.x;
            op[(size_t)(jq * 4 + 1) * TT] = v.y;
            op[(size_t)(jq * 4 + 2) * TT] = v.z;
            op[(size_t)(jq * 4 + 3) * TT] = v.w;
        }
    }
}

// ---- fixup: flagged points, coalesced exact fp64 full scan ----
__global__ __launch_bounds__(256) void vq_fixup(
    const float* __restrict__ x, const float* __restrict__ w,
    const int* __restrict__ cnt, const int* __restrict__ list, int cap,
    float* __restrict__ out)
{
    __shared__ double sd[4];
    __shared__ int    sk[4];
    int n = *cnt; if (n > cap) n = cap;

    for (int i = blockIdx.x; i < n; i += gridDim.x) {
        const int g = list[i];
        const int b = g >> 12;             // TT = 4096
        const int t = g & (TT - 1);
        const float* xp = x + (size_t)b * DD * TT + t;

        const int quarter = threadIdx.x & 3;       // 16 d's each
        const int cbase   = threadIdx.x >> 2;      // 0..63

        double xq[16];
        #pragma unroll
        for (int j = 0; j < 16; ++j)
            xq[j] = (double)xp[(size_t)(quarter * 16 + j) * TT];

        double bd = 1e300; int bk = 0;
        for (int it = 0; it < 16; ++it) {
            const int code = cbase + (it << 6);
            const float4* wr = (const float4*)(w + (size_t)code * DD + quarter * 16);
            double a = 0.0;
            #pragma unroll
            for (int q4 = 0; q4 < 4; ++q4) {
                float4 v = wr[q4];
                double e0 = xq[q4 * 4 + 0] - (double)v.x;
                double e1 = xq[q4 * 4 + 1] - (double)v.y;
                double e2 = xq[q4 * 4 + 2] - (double)v.z;
                double e3 = xq[q4 * 4 + 3] - (double)v.w;
                a = fma(e0, e0, a); a = fma(e1, e1, a);
                a = fma(e2, e2, a); a = fma(e3, e3, a);
            }
            a += __shfl_xor(a, 1, 64);
            a += __shfl_xor(a, 2, 64);
            if (a < bd || (a == bd && code < bk)) { bd = a; bk = code; }
        }
        #pragma unroll
        for (int off = 4; off < 64; off <<= 1) {
            double od = __shfl_xor(bd, off, 64);
            int    ok = __shfl_xor(bk, off, 64);
            if (od < bd || (od == bd && ok < bk)) { bd = od; bk = ok; }
        }
        if ((threadIdx.x & 63) == 0) { sd[threadIdx.x >> 6] = bd; sk[threadIdx.x >> 6] = bk; }
        __syncthreads();
        double fb = sd[0]; int fk = sk[0];
        #pragma unroll
        for (int wvi = 1; wvi < 4; ++wvi)
            if (sd[wvi] < fb || (sd[wvi] == fb && sk[wvi] < fk)) { fb = sd[wvi]; fk = sk[wvi]; }

        if (threadIdx.x == 0)
            out[(size_t)BB * DD * TT + g] = (float)fk;
        if (threadIdx.x < 64)
            out[(size_t)b * DD * TT + (size_t)threadIdx.x * TT + t] = w[(size_t)fk * DD + threadIdx.x];
        __syncthreads();   // sd/sk reuse across iterations
    }
}

extern "C" void kernel_launch(void* const* d_in, const int* in_sizes, int n_in,
                              void* d_out, int out_size, void* d_ws, size_t ws_size,
                              hipStream_t stream) {
    const float* x      = (const float*)d_in[0];
    const float* weight = (const float*)d_in[1];
    float* out = (float*)d_out;

    float* bias     = (float*)d_ws;
    _Float16* rec   = (_Float16*)((char*)d_ws + REC_OFF);
    int* cnt        = (int*)((char*)d_ws + CNT_OFF);
    int* list       = (int*)((char*)d_ws + LIST_OFF);
    long long avail = (long long)ws_size - LIST_OFF;
    int cap = avail > 0 ? (int)(avail / 4) : 0;
    if (cap > BB * TT) cap = BB * TT;

    vq_prep<<<32, 256, 0, stream>>>(weight, bias, rec, cnt);
    vq_main<<<(BB * TT) / 128, 256, 0, stream>>>(x, weight, bias, rec, cnt, list, cap, out);
    vq_fixup<<<1024, 256, 0, stream>>>(x, weight, cnt, list, cap, out);
}

// Round 8
// 84.388 us; speedup vs baseline: 1.2254x; 1.0153x over previous
//
#include <hip/hip_runtime.h>

// VQ codebook assign: argmin_k ||x-w_k||^2 = argmax_k (x.w_k - 0.5||w_k||^2)
// Round 8: hide remaining latency + fix write amplification.
//  - bias prefetched in loadA (regs, 1 chunk ahead) -> no mid-compute L2 stall
//  - epilogue via LDS s_idx so every quantized store is a 256B contiguous
//    segment (round-7's 128B segments doubled WRITE_SIZE: 65.5 vs 34 MB)
//  - otherwise: 32 pts/wave, grid 1024, 4 blocks/CU, single-pass FP16 MFMA,
//    EPS_GAP=1/64 (~5 sigma of fp16 score noise), worklist + fp64 fixup.
//
// ws: bias[1024]f32 @0 | rec fp16 @4096 (128KB) | cnt @135168 | list @135184

#define BB 32
#define DD 64
#define TT 4096
#define KK 1024
#define EPS_GAP 0.015625f

#define REC_OFF  4096
#define CNT_OFF  135168
#define LIST_OFF 135184

typedef __attribute__((ext_vector_type(8))) _Float16 half8;
typedef __attribute__((ext_vector_type(4))) float f32x4;

// ---- prep: weight -> swizzled fp16 A-frag records + bias; reset cnt ----
// record r = kc*4 + ks*2 + c (0..127): lane l holds code kc*32+c*16+(l&15),
// d = ks*32+(l>>4)*8+e, 8 halves = 16B. 128 recs * 1KB = 128KB.
__global__ __launch_bounds__(256) void vq_prep(
    const float* __restrict__ w, float* __restrict__ bias,
    _Float16* __restrict__ rec, int* __restrict__ cnt)
{
    const int g    = blockIdx.x * 256 + threadIdx.x;   // 0..8191
    if (g == 0) *cnt = 0;
    const int lane = g & 63;
    const int r    = g >> 6;                           // record 0..127
    const int kc   = r >> 2, ks = (r >> 1) & 1, c = r & 1;
    const int code  = kc * 32 + c * 16 + (lane & 15);
    const int dbase = ks * 32 + (lane >> 4) * 8;

    const float* src = w + (size_t)code * DD + dbase;
    float4 f0 = *(const float4*)src;
    float4 f1 = *(const float4*)(src + 4);
    half8 hv;
    hv[0] = (_Float16)f0.x; hv[1] = (_Float16)f0.y;
    hv[2] = (_Float16)f0.z; hv[3] = (_Float16)f0.w;
    hv[4] = (_Float16)f1.x; hv[5] = (_Float16)f1.y;
    hv[6] = (_Float16)f1.z; hv[7] = (_Float16)f1.w;
    *(half8*)(rec + (size_t)r * 512 + lane * 8) = hv;

    if (g < KK) {
        const float4* wp = (const float4*)(w + (size_t)g * DD);
        float s = 0.f;
        #pragma unroll
        for (int j = 0; j < 16; ++j) {
            float4 v = wp[j];
            s += v.x * v.x + v.y * v.y + v.z * v.z + v.w * v.w;
        }
        bias[g] = -0.5f * s;
    }
}

// ---- main: 4 waves x 32 points per block, 1024 blocks (4 blocks/CU) ----
__global__ __launch_bounds__(256, 4) void vq_main(
    const float* __restrict__ x,
    const float* __restrict__ weight,
    const float* __restrict__ bias,
    const _Float16* __restrict__ rec,
    int* __restrict__ cnt, int* __restrict__ list, int cap,
    float* __restrict__ out)
{
    __shared__ int s_idx[128];

    const int tid  = threadIdx.x;
    const int lane = tid & 63;
    const int wv   = tid >> 6;
    const int b    = blockIdx.x >> 5;                  // 32 tiles of 128 pts per batch
    const int t0   = (blockIdx.x & 31) << 7;
    const int col  = lane & 15, kg = lane >> 4;

    // x -> fp16 B-frags straight from global
    half8 Bf[2][2];                                    // [pt-tile][kstep]
    {
        const float* xb = x + (size_t)b * DD * TT + t0 + wv * 32 + col;
        #pragma unroll
        for (int p = 0; p < 2; ++p)
            #pragma unroll
            for (int ks = 0; ks < 2; ++ks) {
                half8 hv;
                #pragma unroll
                for (int e = 0; e < 8; ++e)
                    hv[e] = (_Float16)xb[(size_t)(ks * 32 + kg * 8 + e) * TT + p * 16];
                Bf[p][ks] = hv;
            }
    }

    float s1[2] = {-1e30f, -1e30f};
    float s2[2] = {-1e30f, -1e30f};
    int   k1[2] = {0, 0};

    // loadA prefetches BOTH the A-frags and the bias C-in vectors (regs)
    auto loadA = [&](int kc, half8 (*A)[2], f32x4* Bv) {
        #pragma unroll
        for (int ks = 0; ks < 2; ++ks)
            #pragma unroll
            for (int c = 0; c < 2; ++c)
                A[ks][c] = *(const half8*)(rec + (size_t)(kc * 4 + ks * 2 + c) * 512 + lane * 8);
        #pragma unroll
        for (int c = 0; c < 2; ++c)
            Bv[c] = *(const f32x4*)(bias + kc * 32 + c * 16 + kg * 4);
    };
    auto compute = [&](int kc, half8 (*A)[2], f32x4* Bv) {
        f32x4 acc[2][2];                               // [c-tile][pt-tile]
        #pragma unroll
        for (int c = 0; c < 2; ++c)
            #pragma unroll
            for (int p = 0; p < 2; ++p) {
                acc[c][p] = __builtin_amdgcn_mfma_f32_16x16x32_f16(A[0][c], Bf[p][0], Bv[c], 0, 0, 0);
                acc[c][p] = __builtin_amdgcn_mfma_f32_16x16x32_f16(A[1][c], Bf[p][1], acc[c][p], 0, 0, 0);
            }
        #pragma unroll
        for (int p = 0; p < 2; ++p)
            #pragma unroll
            for (int c = 0; c < 2; ++c)
                #pragma unroll
                for (int r = 0; r < 4; ++r) {
                    const float s = acc[c][p][r];
                    const int code = kc * 32 + c * 16 + kg * 4 + r;
                    const float ns2 = fmaxf(fminf(s, s1[p]), s2[p]);
                    if (s > s1[p]) { k1[p] = code; s1[p] = s; }
                    s2[p] = ns2;
                }
    };

    // K loop: 32 chunks, 2-stage prefetch pipeline (A + bias both prefetched)
    half8 A0[2][2], A1[2][2];
    f32x4 Bv0[2], Bv1[2];
    loadA(0, A0, Bv0);
    for (int kc = 0; kc < 32; kc += 2) {
        loadA(kc + 1, A1, Bv1);
        compute(kc, A0, Bv0);
        if (kc + 2 < 32) loadA(kc + 2, A0, Bv0);
        compute(kc + 1, A1, Bv1);
    }

    // cross-lane merge: lanes l, l^16, l^32, l^48 share a point
    #pragma unroll
    for (int p = 0; p < 2; ++p) {
        #pragma unroll
        for (int off = 16; off < 64; off <<= 1) {
            float o1 = __shfl_xor(s1[p], off, 64);
            float o2 = __shfl_xor(s2[p], off, 64);
            int   ok = __shfl_xor(k1[p], off, 64);
            bool takeo = (o1 > s1[p]) || (o1 == s1[p] && ok < k1[p]);
            float ns2 = fmaxf(fminf(s1[p], o1), fmaxf(s2[p], o2));
            if (takeo) { s1[p] = o1; k1[p] = ok; }
            s2[p] = ns2;
        }

        // near-tie: push to worklist (fixup kernel resolves exactly)
        bool flag = (lane < 16) && ((s1[p] - s2[p]) <= EPS_GAP);
        int slot = -1;
        if (flag) slot = atomicAdd(cnt, 1);
        if (flag && slot < cap)
            list[slot] = b * TT + t0 + wv * 32 + p * 16 + lane;

        // overflow fallback: inline exact fp64 re-scan (practically never)
        unsigned long long m = __ballot(flag && slot >= cap);
        while (m) {
            const int ptt = __ffsll(m) - 1; m &= m - 1;
            const int t = t0 + wv * 32 + p * 16 + ptt;
            const float* xp = x + (size_t)b * DD * TT + t;
            double bd = 1e300; int bk = 0;
            for (int j = 0; j < 16; ++j) {
                const int k = lane + 64 * j;
                const float* wk = weight + (size_t)k * DD;
                double a0 = 0.0, a1 = 0.0;
                #pragma unroll
                for (int d = 0; d < DD; d += 2) {
                    double e0 = (double)xp[(size_t)d * TT]       - (double)wk[d];
                    double e1 = (double)xp[(size_t)(d + 1) * TT] - (double)wk[d + 1];
                    a0 = fma(e0, e0, a0);
                    a1 = fma(e1, e1, a1);
                }
                const double dist = a0 + a1;
                if (dist < bd || (dist == bd && k < bk)) { bd = dist; bk = k; }
            }
            #pragma unroll
            for (int off = 1; off < 64; off <<= 1) {
                double od = __shfl_xor(bd, off, 64);
                int    okk = __shfl_xor(bk, off, 64);
                if (od < bd || (od == bd && okk < bk)) { bd = od; bk = okk; }
            }
            if ((lane & 15) == ptt) k1[p] = bk;
        }

        if (lane < 16) s_idx[wv * 32 + p * 16 + lane] = k1[p];
    }
    __syncthreads();

    // ---- epilogue: every store instruction = 256B contiguous segment ----
    // indices (as float): 128 threads, 512B contiguous
    if (tid < 128)
        out[(size_t)BB * DD * TT + (size_t)b * TT + t0 + tid] = (float)s_idx[tid];

    // quantized: thread = (pt = tid&127, dh = tid>>7 covering 32 d's).
    // Wave w's 64 lanes share one dh and cover 64 consecutive pts -> 256B/store.
    {
        const int pt = tid & 127;
        const int dh = tid >> 7;
        const int kq = s_idx[pt];
        const float4* wr = (const float4*)(weight + (size_t)kq * DD + dh * 32);
        float* op = out + ((size_t)b * DD + dh * 32) * TT + t0 + pt;
        #pragma unroll
        for (int jq = 0; jq < 8; ++jq) {
            float4 v = wr[jq];
            op[(size_t)(jq * 4 + 0) * TT] = v.x;
            op[(size_t)(jq * 4 + 1) * TT] = v.y;
            op[(size_t)(jq * 4 + 2) * TT] = v.z;
            op[(size_t)(jq * 4 + 3) * TT] = v.w;
        }
    }
}

// ---- fixup: flagged points, coalesced exact fp64 full scan ----
__global__ __launch_bounds__(256) void vq_fixup(
    const float* __restrict__ x, const float* __restrict__ w,
    const int* __restrict__ cnt, const int* __restrict__ list, int cap,
    float* __restrict__ out)
{
    __shared__ double sd[4];
    __shared__ int    sk[4];
    int n = *cnt; if (n > cap) n = cap;

    for (int i = blockIdx.x; i < n; i += gridDim.x) {
        const int g = list[i];
        const int b = g >> 12;             // TT = 4096
        const int t = g & (TT - 1);
        const float* xp = x + (size_t)b * DD * TT + t;

        const int quarter = threadIdx.x & 3;       // 16 d's each
        const int cbase   = threadIdx.x >> 2;      // 0..63

        double xq[16];
        #pragma unroll
        for (int j = 0; j < 16; ++j)
            xq[j] = (double)xp[(size_t)(quarter * 16 + j) * TT];

        double bd = 1e300; int bk = 0;
        for (int it = 0; it < 16; ++it) {
            const int code = cbase + (it << 6);
            const float4* wr = (const float4*)(w + (size_t)code * DD + quarter * 16);
            double a = 0.0;
            #pragma unroll
            for (int q4 = 0; q4 < 4; ++q4) {
                float4 v = wr[q4];
                double e0 = xq[q4 * 4 + 0] - (double)v.x;
                double e1 = xq[q4 * 4 + 1] - (double)v.y;
                double e2 = xq[q4 * 4 + 2] - (double)v.z;
                double e3 = xq[q4 * 4 + 3] - (double)v.w;
                a = fma(e0, e0, a); a = fma(e1, e1, a);
                a = fma(e2, e2, a); a = fma(e3, e3, a);
            }
            a += __shfl_xor(a, 1, 64);
            a += __shfl_xor(a, 2, 64);
            if (a < bd || (a == bd && code < bk)) { bd = a; bk = code; }
        }
        #pragma unroll
        for (int off = 4; off < 64; off <<= 1) {
            double od = __shfl_xor(bd, off, 64);
            int    ok = __shfl_xor(bk, off, 64);
            if (od < bd || (od == bd && ok < bk)) { bd = od; bk = ok; }
        }
        if ((threadIdx.x & 63) == 0) { sd[threadIdx.x >> 6] = bd; sk[threadIdx.x >> 6] = bk; }
        __syncthreads();
        double fb = sd[0]; int fk = sk[0];
        #pragma unroll
        for (int wvi = 1; wvi < 4; ++wvi)
            if (sd[wvi] < fb || (sd[wvi] == fb && sk[wvi] < fk)) { fb = sd[wvi]; fk = sk[wvi]; }

        if (threadIdx.x == 0)
            out[(size_t)BB * DD * TT + g] = (float)fk;
        if (threadIdx.x < 64)
            out[(size_t)b * DD * TT + (size_t)threadIdx.x * TT + t] = w[(size_t)fk * DD + threadIdx.x];
        __syncthreads();   // sd/sk reuse across iterations
    }
}

extern "C" void kernel_launch(void* const* d_in, const int* in_sizes, int n_in,
                              void* d_out, int out_size, void* d_ws, size_t ws_size,
                              hipStream_t stream) {
    const float* x      = (const float*)d_in[0];
    const float* weight = (const float*)d_in[1];
    float* out = (float*)d_out;

    float* bias     = (float*)d_ws;
    _Float16* rec   = (_Float16*)((char*)d_ws + REC_OFF);
    int* cnt        = (int*)((char*)d_ws + CNT_OFF);
    int* list       = (int*)((char*)d_ws + LIST_OFF);
    long long avail = (long long)ws_size - LIST_OFF;
    int cap = avail > 0 ? (int)(avail / 4) : 0;
    if (cap > BB * TT) cap = BB * TT;

    vq_prep<<<32, 256, 0, stream>>>(weight, bias, rec, cnt);
    vq_main<<<(BB * TT) / 128, 256, 0, stream>>>(x, weight, bias, rec, cnt, list, cap, out);
    vq_fixup<<<1024, 256, 0, stream>>>(x, weight, cnt, list, cap, out);
}

// Round 9
// 81.993 us; speedup vs baseline: 1.2613x; 1.0292x over previous
//
#include <hip/hip_runtime.h>

// VQ codebook assign: argmin_k ||x-w_k||^2 = argmax_k (x.w_k - 0.5||w_k||^2)
// Round 9: split-K waves. 512-thread blocks (8 waves), 256 pts/block:
// wave = (pt-group 0..3 [64 pts], K-half 0/1 [512 codes]). 2 blocks/CU =
// 4 waves/SIMD AND 64 pts/wave amortization AND 1KB output regions (fixes
// the 2x write amplification seen with 128-pt blocks). Top-2 merged across
// K-halves in LDS (exact union-top2, half0 wins ties = first-occurrence).
// Single-pass FP16 MFMA, EPS_GAP=1/64 (~5 sigma), worklist + fp64 fixup.
//
// ws: bias[1024]f32 @0 | rec fp16 @4096 (128KB) | cnt @135168 | list @135184

#define BB 32
#define DD 64
#define TT 4096
#define KK 1024
#define EPS_GAP 0.015625f

#define REC_OFF  4096
#define CNT_OFF  135168
#define LIST_OFF 135184

typedef __attribute__((ext_vector_type(8))) _Float16 half8;
typedef __attribute__((ext_vector_type(4))) float f32x4;

// ---- prep: weight -> swizzled fp16 A-frag records + bias; reset cnt ----
// record r = kc*4 + ks*2 + c (0..127): lane l holds code kc*32+c*16+(l&15),
// d = ks*32+(l>>4)*8+e, 8 halves = 16B. 128 recs * 1KB = 128KB.
__global__ __launch_bounds__(256) void vq_prep(
    const float* __restrict__ w, float* __restrict__ bias,
    _Float16* __restrict__ rec, int* __restrict__ cnt)
{
    const int g    = blockIdx.x * 256 + threadIdx.x;   // 0..8191
    if (g == 0) *cnt = 0;
    const int lane = g & 63;
    const int r    = g >> 6;                           // record 0..127
    const int kc   = r >> 2, ks = (r >> 1) & 1, c = r & 1;
    const int code  = kc * 32 + c * 16 + (lane & 15);
    const int dbase = ks * 32 + (lane >> 4) * 8;

    const float* src = w + (size_t)code * DD + dbase;
    float4 f0 = *(const float4*)src;
    float4 f1 = *(const float4*)(src + 4);
    half8 hv;
    hv[0] = (_Float16)f0.x; hv[1] = (_Float16)f0.y;
    hv[2] = (_Float16)f0.z; hv[3] = (_Float16)f0.w;
    hv[4] = (_Float16)f1.x; hv[5] = (_Float16)f1.y;
    hv[6] = (_Float16)f1.z; hv[7] = (_Float16)f1.w;
    *(half8*)(rec + (size_t)r * 512 + lane * 8) = hv;

    if (g < KK) {
        const float4* wp = (const float4*)(w + (size_t)g * DD);
        float s = 0.f;
        #pragma unroll
        for (int j = 0; j < 16; ++j) {
            float4 v = wp[j];
            s += v.x * v.x + v.y * v.y + v.z * v.z + v.w * v.w;
        }
        bias[g] = -0.5f * s;
    }
}

// ---- main: 8 waves = 4 pt-groups x 2 K-halves; 256 pts/block, 512 blocks ----
__global__ __launch_bounds__(512, 4) void vq_main(
    const float* __restrict__ x,
    const float* __restrict__ weight,
    const float* __restrict__ bias,
    const _Float16* __restrict__ rec,
    int* __restrict__ cnt, int* __restrict__ list, int cap,
    float* __restrict__ out)
{
    __shared__ float s_s1[2][256];
    __shared__ float s_s2[2][256];
    __shared__ int   s_k1[2][256];
    __shared__ int   s_idx[256];

    const int tid   = threadIdx.x;                 // 0..511
    const int lane  = tid & 63;
    const int wv    = tid >> 6;                    // 0..7
    const int pgrp  = wv & 3;                      // 64-pt group
    const int khalf = wv >> 2;                     // 0: codes 0..511, 1: 512..1023
    const int b     = blockIdx.x >> 4;             // 16 tiles of 256 pts per batch
    const int t0    = (blockIdx.x & 15) << 8;
    const int col   = lane & 15, kg = lane >> 4;

    // x -> fp16 B-frags straight from global (both K-half waves load the same
    // 64 points; redundant load is L2/L3-absorbed)
    half8 Bf[4][2];                                // [pt-tile][kstep]
    {
        const float* xb = x + (size_t)b * DD * TT + t0 + pgrp * 64 + col;
        #pragma unroll
        for (int p = 0; p < 4; ++p)
            #pragma unroll
            for (int ks = 0; ks < 2; ++ks) {
                half8 hv;
                #pragma unroll
                for (int e = 0; e < 8; ++e)
                    hv[e] = (_Float16)xb[(size_t)(ks * 32 + kg * 8 + e) * TT + p * 16];
                Bf[p][ks] = hv;
            }
    }

    float s1[4] = {-1e30f, -1e30f, -1e30f, -1e30f};
    float s2[4] = {-1e30f, -1e30f, -1e30f, -1e30f};
    int   k1[4] = {0, 0, 0, 0};

    // loadA prefetches the A-frags AND the bias C-in vectors (regs)
    auto loadA = [&](int kcg, half8 (*A)[2], f32x4* Bv) {
        #pragma unroll
        for (int ks = 0; ks < 2; ++ks)
            #pragma unroll
            for (int c = 0; c < 2; ++c)
                A[ks][c] = *(const half8*)(rec + (size_t)(kcg * 4 + ks * 2 + c) * 512 + lane * 8);
        #pragma unroll
        for (int c = 0; c < 2; ++c)
            Bv[c] = *(const f32x4*)(bias + kcg * 32 + c * 16 + kg * 4);
    };
    auto compute = [&](int kcg, half8 (*A)[2], f32x4* Bv) {
        f32x4 acc[2][4];                           // [c-tile][pt-tile]
        #pragma unroll
        for (int c = 0; c < 2; ++c)
            #pragma unroll
            for (int p = 0; p < 4; ++p) {
                acc[c][p] = __builtin_amdgcn_mfma_f32_16x16x32_f16(A[0][c], Bf[p][0], Bv[c], 0, 0, 0);
                acc[c][p] = __builtin_amdgcn_mfma_f32_16x16x32_f16(A[1][c], Bf[p][1], acc[c][p], 0, 0, 0);
            }
        #pragma unroll
        for (int p = 0; p < 4; ++p)
            #pragma unroll
            for (int c = 0; c < 2; ++c)
                #pragma unroll
                for (int r = 0; r < 4; ++r) {
                    const float s = acc[c][p][r];
                    const int code = kcg * 32 + c * 16 + kg * 4 + r;
                    const float ns2 = fmaxf(fminf(s, s1[p]), s2[p]);
                    if (s > s1[p]) { k1[p] = code; s1[p] = s; }
                    s2[p] = ns2;
                }
    };

    // K loop: 16 chunks (this wave's K-half), 2-stage prefetch pipeline
    half8 A0[2][2], A1[2][2];
    f32x4 Bv0[2], Bv1[2];
    const int kbase = khalf * 16;
    loadA(kbase, A0, Bv0);
    for (int kc = 0; kc < 16; kc += 2) {
        loadA(kbase + kc + 1, A1, Bv1);
        compute(kbase + kc, A0, Bv0);
        if (kc + 2 < 16) loadA(kbase + kc + 2, A0, Bv0);
        compute(kbase + kc + 1, A1, Bv1);
    }

    // intra-wave merge: lanes l, l^16, l^32, l^48 share a point
    #pragma unroll
    for (int p = 0; p < 4; ++p) {
        #pragma unroll
        for (int off = 16; off < 64; off <<= 1) {
            float o1 = __shfl_xor(s1[p], off, 64);
            float o2 = __shfl_xor(s2[p], off, 64);
            int   ok = __shfl_xor(k1[p], off, 64);
            bool takeo = (o1 > s1[p]) || (o1 == s1[p] && ok < k1[p]);
            float ns2 = fmaxf(fminf(s1[p], o1), fmaxf(s2[p], o2));
            if (takeo) { s1[p] = o1; k1[p] = ok; }
            s2[p] = ns2;
        }
        if (lane < 16) {
            const int pt = pgrp * 64 + p * 16 + lane;
            s_s1[khalf][pt] = s1[p];
            s_s2[khalf][pt] = s2[p];
            s_k1[khalf][pt] = k1[p];
        }
    }
    __syncthreads();

    // cross-half union-top2 merge + near-tie flag; one thread per point
    if (tid < 256) {
        const float a1 = s_s1[0][tid], b1 = s_s1[1][tid];
        const float a2 = s_s2[0][tid], b2 = s_s2[1][tid];
        const int   ak = s_k1[0][tid], bk = s_k1[1][tid];
        // ties -> half 0 (lower code) = first-occurrence rule
        const bool aw = (a1 >= b1);
        const float m1 = aw ? a1 : b1;
        const int   mk = aw ? ak : bk;
        const float m2 = fmaxf(fminf(a1, b1), aw ? a2 : b2);
        s_idx[tid] = mk;

        const bool flag = (m1 - m2) <= EPS_GAP;
        int slot = -1;
        if (flag) slot = atomicAdd(cnt, 1);
        if (flag && slot < cap) list[slot] = b * TT + t0 + tid;

        // overflow fallback: exact per-thread fp64 scan (cap >= flags in
        // practice -> dead code, kept for robustness)
        if (flag && slot >= cap) {
            const float* xp = x + (size_t)b * DD * TT + t0 + tid;
            double bd = 1e300; int bkx = 0;
            for (int k = 0; k < KK; ++k) {
                const float* wk = weight + (size_t)k * DD;
                double a0 = 0.0;
                for (int d = 0; d < DD; ++d) {
                    double e = (double)xp[(size_t)d * TT] - (double)wk[d];
                    a0 = fma(e, e, a0);
                }
                if (a0 < bd) { bd = a0; bkx = k; }
            }
            s_idx[tid] = bkx;
        }
    }
    __syncthreads();

    // ---- epilogue: 256-pt tiles -> 1KB contiguous regions per (b,d) ----
    // indices (as float): 256 threads, 1KB contiguous
    if (tid < 256)
        out[(size_t)BB * DD * TT + (size_t)b * TT + t0 + tid] = (float)s_idx[tid];

    // quantized: thread = (pt = tid&255, dh = tid>>8 covering 32 d's).
    // Each wave: 64 consecutive pts, fixed dh -> 256B/store; 1KB per (b,d).
    {
        const int pt = tid & 255;
        const int dh = tid >> 8;
        const int kq = s_idx[pt];
        const float4* wr = (const float4*)(weight + (size_t)kq * DD + dh * 32);
        float* op = out + ((size_t)b * DD + dh * 32) * TT + t0 + pt;
        #pragma unroll
        for (int jq = 0; jq < 8; ++jq) {
            float4 v = wr[jq];
            op[(size_t)(jq * 4 + 0) * TT] = v.x;
            op[(size_t)(jq * 4 + 1) * TT] = v.y;
            op[(size_t)(jq * 4 + 2) * TT] = v.z;
            op[(size_t)(jq * 4 + 3) * TT] = v.w;
        }
    }
}

// ---- fixup: flagged points, coalesced exact fp64 full scan ----
__global__ __launch_bounds__(256) void vq_fixup(
    const float* __restrict__ x, const float* __restrict__ w,
    const int* __restrict__ cnt, const int* __restrict__ list, int cap,
    float* __restrict__ out)
{
    __shared__ double sd[4];
    __shared__ int    sk[4];
    int n = *cnt; if (n > cap) n = cap;

    for (int i = blockIdx.x; i < n; i += gridDim.x) {
        const int g = list[i];
        const int b = g >> 12;             // TT = 4096
        const int t = g & (TT - 1);
        const float* xp = x + (size_t)b * DD * TT + t;

        const int quarter = threadIdx.x & 3;       // 16 d's each
        const int cbase   = threadIdx.x >> 2;      // 0..63

        double xq[16];
        #pragma unroll
        for (int j = 0; j < 16; ++j)
            xq[j] = (double)xp[(size_t)(quarter * 16 + j) * TT];

        double bd = 1e300; int bk = 0;
        for (int it = 0; it < 16; ++it) {
            const int code = cbase + (it << 6);
            const float4* wr = (const float4*)(w + (size_t)code * DD + quarter * 16);
            double a = 0.0;
            #pragma unroll
            for (int q4 = 0; q4 < 4; ++q4) {
                float4 v = wr[q4];
                double e0 = xq[q4 * 4 + 0] - (double)v.x;
                double e1 = xq[q4 * 4 + 1] - (double)v.y;
                double e2 = xq[q4 * 4 + 2] - (double)v.z;
                double e3 = xq[q4 * 4 + 3] - (double)v.w;
                a = fma(e0, e0, a); a = fma(e1, e1, a);
                a = fma(e2, e2, a); a = fma(e3, e3, a);
            }
            a += __shfl_xor(a, 1, 64);
            a += __shfl_xor(a, 2, 64);
            if (a < bd || (a == bd && code < bk)) { bd = a; bk = code; }
        }
        #pragma unroll
        for (int off = 4; off < 64; off <<= 1) {
            double od = __shfl_xor(bd, off, 64);
            int    ok = __shfl_xor(bk, off, 64);
            if (od < bd || (od == bd && ok < bk)) { bd = od; bk = ok; }
        }
        if ((threadIdx.x & 63) == 0) { sd[threadIdx.x >> 6] = bd; sk[threadIdx.x >> 6] = bk; }
        __syncthreads();
        double fb = sd[0]; int fk = sk[0];
        #pragma unroll
        for (int wvi = 1; wvi < 4; ++wvi)
            if (sd[wvi] < fb || (sd[wvi] == fb && sk[wvi] < fk)) { fb = sd[wvi]; fk = sk[wvi]; }

        if (threadIdx.x == 0)
            out[(size_t)BB * DD * TT + g] = (float)fk;
        if (threadIdx.x < 64)
            out[(size_t)b * DD * TT + (size_t)threadIdx.x * TT + t] = w[(size_t)fk * DD + threadIdx.x];
        __syncthreads();   // sd/sk reuse across iterations
    }
}

extern "C" void kernel_launch(void* const* d_in, const int* in_sizes, int n_in,
                              void* d_out, int out_size, void* d_ws, size_t ws_size,
                              hipStream_t stream) {
    const float* x      = (const float*)d_in[0];
    const float* weight = (const float*)d_in[1];
    float* out = (float*)d_out;

    float* bias     = (float*)d_ws;
    _Float16* rec   = (_Float16*)((char*)d_ws + REC_OFF);
    int* cnt        = (int*)((char*)d_ws + CNT_OFF);
    int* list       = (int*)((char*)d_ws + LIST_OFF);
    long long avail = (long long)ws_size - LIST_OFF;
    int cap = avail > 0 ? (int)(avail / 4) : 0;
    if (cap > BB * TT) cap = BB * TT;

    vq_prep<<<32, 256, 0, stream>>>(weight, bias, rec, cnt);
    vq_main<<<(BB * TT) / 256, 512, 0, stream>>>(x, weight, bias, rec, cnt, list, cap, out);
    vq_fixup<<<1024, 256, 0, stream>>>(x, weight, cnt, list, cap, out);
}

// Round 10
// 67.901 us; speedup vs baseline: 1.5230x; 1.2075x over previous
//
#include <hip/hip_runtime.h>

// VQ codebook assign: argmin_k ||x-w_k||^2 = argmax_k (x.w_k - 0.5||w_k||^2)
// Round 10: LDS-resident codebook. Rounds 6-9 proved duration is invariant
// to TLP (61us at both 8 and 16 waves/CU) -> K-loop is L2-latency-bound on
// the rec/bias stream. Fix: stage rec (128KB fp16) + bias (4KB) into LDS
// once per block; K-loop reads become ds_read_b128 (~120cy, hidden by the
// 2-chunk register prefetch). 512-thr/8-wave blocks, 64 pts/wave, FULL K per
// wave (no split-K, no redundant x loads, intra-wave merge only), grid 256
// = 1 block/CU (LDS-capped). 512-pt output tiles -> 2KB write regions.
// fmed3 s2-update (exact given s2<=s1). Batched worklist atomic.
// Exactness: fp16 single-pass + EPS_GAP=1/64 (~5 sigma) + fp64 fixup kernel.
//
// ws: bias[1024]f32 @0 | rec fp16 @4096 (128KB) | cnt @135168 | list @135184

#define BB 32
#define DD 64
#define TT 4096
#define KK 1024
#define EPS_GAP 0.015625f

#define REC_OFF  4096
#define CNT_OFF  135168
#define LIST_OFF 135184

#define LDS_BYTES (131072 + 4096 + 2048)   // rec + bias + s_idx

typedef __attribute__((ext_vector_type(8))) _Float16 half8;
typedef __attribute__((ext_vector_type(4))) float f32x4;

// ---- prep: weight -> swizzled fp16 A-frag records + bias; reset cnt ----
// record r = kc*4 + ks*2 + c (0..127): lane l holds code kc*32+c*16+(l&15),
// d = ks*32+(l>>4)*8+e, 8 halves = 16B. 128 recs * 1KB = 128KB.
__global__ __launch_bounds__(256) void vq_prep(
    const float* __restrict__ w, float* __restrict__ bias,
    _Float16* __restrict__ rec, int* __restrict__ cnt)
{
    const int g    = blockIdx.x * 256 + threadIdx.x;   // 0..8191
    if (g == 0) *cnt = 0;
    const int lane = g & 63;
    const int r    = g >> 6;                           // record 0..127
    const int kc   = r >> 2, ks = (r >> 1) & 1, c = r & 1;
    const int code  = kc * 32 + c * 16 + (lane & 15);
    const int dbase = ks * 32 + (lane >> 4) * 8;

    const float* src = w + (size_t)code * DD + dbase;
    float4 f0 = *(const float4*)src;
    float4 f1 = *(const float4*)(src + 4);
    half8 hv;
    hv[0] = (_Float16)f0.x; hv[1] = (_Float16)f0.y;
    hv[2] = (_Float16)f0.z; hv[3] = (_Float16)f0.w;
    hv[4] = (_Float16)f1.x; hv[5] = (_Float16)f1.y;
    hv[6] = (_Float16)f1.z; hv[7] = (_Float16)f1.w;
    *(half8*)(rec + (size_t)r * 512 + lane * 8) = hv;

    if (g < KK) {
        const float4* wp = (const float4*)(w + (size_t)g * DD);
        float s = 0.f;
        #pragma unroll
        for (int j = 0; j < 16; ++j) {
            float4 v = wp[j];
            s += v.x * v.x + v.y * v.y + v.z * v.z + v.w * v.w;
        }
        bias[g] = -0.5f * s;
    }
}

// ---- main: 8 waves x 64 pts (full K each); 512 pts/block, 256 blocks ----
__global__ __launch_bounds__(512, 1) void vq_main(
    const float* __restrict__ x,
    const float* __restrict__ weight,
    const float* __restrict__ bias,
    const _Float16* __restrict__ rec,
    int* __restrict__ cnt, int* __restrict__ list, int cap,
    float* __restrict__ out)
{
    extern __shared__ char smem[];
    _Float16* l_rec  = (_Float16*)smem;                    // [128][512] halves
    float*    l_bias = (float*)(smem + 131072);            // [1024]
    int*      s_idx  = (int*)(smem + 131072 + 4096);       // [512]

    const int tid  = threadIdx.x;                  // 0..511
    const int lane = tid & 63;
    const int wv   = tid >> 6;                     // 0..7
    const int bb   = blockIdx.x >> 3;              // 8 tiles of 512 pts per batch
    const int t0   = (blockIdx.x & 7) << 9;
    const int col  = lane & 15, kg = lane >> 4;

    // ---- stage rec + bias into LDS (coalesced int4 copies) ----
    {
        const int4* src = (const int4*)rec;        // 8192 int4 = 128KB
        int4* dst = (int4*)l_rec;
        #pragma unroll
        for (int s = 0; s < 16; ++s)
            dst[s * 512 + tid] = src[s * 512 + tid];
        ((float2*)l_bias)[tid] = ((const float2*)bias)[tid];   // 512*8B = 4KB
    }

    // ---- x -> fp16 B-frags straight from global (overlaps staging wait) ----
    half8 Bf[4][2];                                // [pt-tile][kstep]
    {
        const float* xb = x + (size_t)bb * DD * TT + t0 + wv * 64 + col;
        #pragma unroll
        for (int p = 0; p < 4; ++p)
            #pragma unroll
            for (int ks = 0; ks < 2; ++ks) {
                half8 hv;
                #pragma unroll
                for (int e = 0; e < 8; ++e)
                    hv[e] = (_Float16)xb[(size_t)(ks * 32 + kg * 8 + e) * TT + p * 16];
                Bf[p][ks] = hv;
            }
    }
    __syncthreads();

    float s1[4] = {-1e30f, -1e30f, -1e30f, -1e30f};
    float s2[4] = {-1e30f, -1e30f, -1e30f, -1e30f};
    int   k1[4] = {0, 0, 0, 0};

    // loadA: A-frags + bias C-in from LDS (ds_read_b128, 2-way bank = free)
    auto loadA = [&](int kc, half8 (*A)[2], f32x4* Bv) {
        #pragma unroll
        for (int ks = 0; ks < 2; ++ks)
            #pragma unroll
            for (int c = 0; c < 2; ++c)
                A[ks][c] = *(const half8*)(l_rec + (kc * 4 + ks * 2 + c) * 512 + lane * 8);
        #pragma unroll
        for (int c = 0; c < 2; ++c)
            Bv[c] = *(const f32x4*)(l_bias + kc * 32 + c * 16 + kg * 4);
    };
    auto compute = [&](int kc, half8 (*A)[2], f32x4* Bv) {
        f32x4 acc[2][4];                           // [c-tile][pt-tile]
        #pragma unroll
        for (int c = 0; c < 2; ++c)
            #pragma unroll
            for (int p = 0; p < 4; ++p) {
                acc[c][p] = __builtin_amdgcn_mfma_f32_16x16x32_f16(A[0][c], Bf[p][0], Bv[c], 0, 0, 0);
                acc[c][p] = __builtin_amdgcn_mfma_f32_16x16x32_f16(A[1][c], Bf[p][1], acc[c][p], 0, 0, 0);
            }
        #pragma unroll
        for (int p = 0; p < 4; ++p)
            #pragma unroll
            for (int c = 0; c < 2; ++c)
                #pragma unroll
                for (int r = 0; r < 4; ++r) {
                    const float s = acc[c][p][r];
                    const int code = kc * 32 + c * 16 + kg * 4 + r;
                    // s2<=s1 invariant -> med3(s,s1,s2) == new second-best
                    const float ns2 = __builtin_amdgcn_fmed3f(s, s1[p], s2[p]);
                    if (s > s1[p]) { k1[p] = code; s1[p] = s; }
                    s2[p] = ns2;
                }
    };

    // K loop: 32 chunks, 2-stage register prefetch from LDS
    half8 A0[2][2], A1[2][2];
    f32x4 Bv0[2], Bv1[2];
    loadA(0, A0, Bv0);
    for (int kc = 0; kc < 32; kc += 2) {
        loadA(kc + 1, A1, Bv1);
        compute(kc, A0, Bv0);
        if (kc + 2 < 32) loadA(kc + 2, A0, Bv0);
        compute(kc + 1, A1, Bv1);
    }

    // intra-wave merge: lanes l, l^16, l^32, l^48 share a point
    #pragma unroll
    for (int p = 0; p < 4; ++p) {
        #pragma unroll
        for (int off = 16; off < 64; off <<= 1) {
            float o1 = __shfl_xor(s1[p], off, 64);
            float o2 = __shfl_xor(s2[p], off, 64);
            int   ok = __shfl_xor(k1[p], off, 64);
            bool takeo = (o1 > s1[p]) || (o1 == s1[p] && ok < k1[p]);
            float ns2 = fmaxf(fminf(s1[p], o1), fmaxf(s2[p], o2));
            if (takeo) { s1[p] = o1; k1[p] = ok; }
            s2[p] = ns2;
        }

        // near-tie: batched push to worklist (one atomic per wave per p)
        const bool flag = (lane < 16) && ((s1[p] - s2[p]) <= EPS_GAP);
        unsigned long long m = __ballot(flag);
        if (m) {
            int base = 0;
            if (lane == 0) base = atomicAdd(cnt, __popcll(m));
            base = __shfl(base, 0, 64);
            if (flag) {
                const int my = base + __popcll(m & ((1ull << lane) - 1));
                if (my < cap) {
                    list[my] = bb * TT + t0 + wv * 64 + p * 16 + lane;
                } else {
                    // overflow fallback: exact per-lane fp64 scan (never in practice)
                    const float* xp = x + (size_t)bb * DD * TT + t0 + wv * 64 + p * 16 + lane;
                    double bd = 1e300; int bk2 = 0;
                    for (int k = 0; k < KK; ++k) {
                        const float* wk = weight + (size_t)k * DD;
                        double a0 = 0.0;
                        for (int d = 0; d < DD; ++d) {
                            double e = (double)xp[(size_t)d * TT] - (double)wk[d];
                            a0 = fma(e, e, a0);
                        }
                        if (a0 < bd) { bd = a0; bk2 = k; }
                    }
                    k1[p] = bk2;
                }
            }
        }
        if (lane < 16) s_idx[wv * 64 + p * 16 + lane] = k1[p];
    }
    __syncthreads();

    // ---- epilogue: 512-pt tiles -> 2KB contiguous regions per (b,d) ----
    // indices (as float): 512 threads, 2KB contiguous
    out[(size_t)BB * DD * TT + (size_t)bb * TT + t0 + tid] = (float)s_idx[tid];

    // quantized: thread = point, writes its full 64-d column; lanes are
    // consecutive points -> 256B/store, 2KB per (b,d) row per block
    {
        const int kq = s_idx[tid];
        const float4* wr = (const float4*)(weight + (size_t)kq * DD);
        float* op = out + (size_t)bb * DD * TT + t0 + tid;
        #pragma unroll
        for (int jq = 0; jq < 16; ++jq) {
            float4 v = wr[jq];
            op[(size_t)(jq * 4 + 0) * TT] = v.x;
            op[(size_t)(jq * 4 + 1) * TT] = v.y;
            op[(size_t)(jq * 4 + 2) * TT] = v.z;
            op[(size_t)(jq * 4 + 3) * TT] = v.w;
        }
    }
}

// ---- fixup: flagged points, coalesced exact fp64 full scan ----
__global__ __launch_bounds__(256) void vq_fixup(
    const float* __restrict__ x, const float* __restrict__ w,
    const int* __restrict__ cnt, const int* __restrict__ list, int cap,
    float* __restrict__ out)
{
    __shared__ double sd[4];
    __shared__ int    sk[4];
    int n = *cnt; if (n > cap) n = cap;

    for (int i = blockIdx.x; i < n; i += gridDim.x) {
        const int g = list[i];
        const int b = g >> 12;             // TT = 4096
        const int t = g & (TT - 1);
        const float* xp = x + (size_t)b * DD * TT + t;

        const int quarter = threadIdx.x & 3;       // 16 d's each
        const int cbase   = threadIdx.x >> 2;      // 0..63

        double xq[16];
        #pragma unroll
        for (int j = 0; j < 16; ++j)
            xq[j] = (double)xp[(size_t)(quarter * 16 + j) * TT];

        double bd = 1e300; int bk = 0;
        for (int it = 0; it < 16; ++it) {
            const int code = cbase + (it << 6);
            const float4* wr = (const float4*)(w + (size_t)code * DD + quarter * 16);
            double a = 0.0;
            #pragma unroll
            for (int q4 = 0; q4 < 4; ++q4) {
                float4 v = wr[q4];
                double e0 = xq[q4 * 4 + 0] - (double)v.x;
                double e1 = xq[q4 * 4 + 1] - (double)v.y;
                double e2 = xq[q4 * 4 + 2] - (double)v.z;
                double e3 = xq[q4 * 4 + 3] - (double)v.w;
                a = fma(e0, e0, a); a = fma(e1, e1, a);
                a = fma(e2, e2, a); a = fma(e3, e3, a);
            }
            a += __shfl_xor(a, 1, 64);
            a += __shfl_xor(a, 2, 64);
            if (a < bd || (a == bd && code < bk)) { bd = a; bk = code; }
        }
        #pragma unroll
        for (int off = 4; off < 64; off <<= 1) {
            double od = __shfl_xor(bd, off, 64);
            int    ok = __shfl_xor(bk, off, 64);
            if (od < bd || (od == bd && ok < bk)) { bd = od; bk = ok; }
        }
        if ((threadIdx.x & 63) == 0) { sd[threadIdx.x >> 6] = bd; sk[threadIdx.x >> 6] = bk; }
        __syncthreads();
        double fb = sd[0]; int fk = sk[0];
        #pragma unroll
        for (int wvi = 1; wvi < 4; ++wvi)
            if (sd[wvi] < fb || (sd[wvi] == fb && sk[wvi] < fk)) { fb = sd[wvi]; fk = sk[wvi]; }

        if (threadIdx.x == 0)
            out[(size_t)BB * DD * TT + g] = (float)fk;
        if (threadIdx.x < 64)
            out[(size_t)b * DD * TT + (size_t)threadIdx.x * TT + t] = w[(size_t)fk * DD + threadIdx.x];
        __syncthreads();   // sd/sk reuse across iterations
    }
}

extern "C" void kernel_launch(void* const* d_in, const int* in_sizes, int n_in,
                              void* d_out, int out_size, void* d_ws, size_t ws_size,
                              hipStream_t stream) {
    const float* x      = (const float*)d_in[0];
    const float* weight = (const float*)d_in[1];
    float* out = (float*)d_out;

    float* bias     = (float*)d_ws;
    _Float16* rec   = (_Float16*)((char*)d_ws + REC_OFF);
    int* cnt        = (int*)((char*)d_ws + CNT_OFF);
    int* list       = (int*)((char*)d_ws + LIST_OFF);
    long long avail = (long long)ws_size - LIST_OFF;
    int cap = avail > 0 ? (int)(avail / 4) : 0;
    if (cap > BB * TT) cap = BB * TT;

    vq_prep<<<32, 256, 0, stream>>>(weight, bias, rec, cnt);
    vq_main<<<(BB * TT) / 512, 512, LDS_BYTES, stream>>>(x, weight, bias, rec, cnt, list, cap, out);
    vq_fixup<<<1024, 256, 0, stream>>>(x, weight, cnt, list, cap, out);
}